// Round 1
// baseline (3114.211 us; speedup 1.0000x reference)
//
#include <hip/hip_runtime.h>

#define NN 100000
#define NE 1600000
#define DD 64

// ---------------- zero ----------------
__global__ void zero_kernel(float* __restrict__ p, int n) {
  int i = blockIdx.x * blockDim.x + threadIdx.x;
  int stride = gridDim.x * blockDim.x;
  for (; i < n; i += stride) p[i] = 0.0f;
}

// ---------------- scatter-add (segment_sum) ----------------
// 16 threads per edge, each handles 4 contiguous floats (float4 gather).
__global__ void scatter_kernel(const float* __restrict__ x,
                               const int* __restrict__ src,
                               const int* __restrict__ dst,
                               float* __restrict__ s,
                               float* __restrict__ cnt,
                               int do_cnt) {
  int tid = blockIdx.x * 256 + threadIdx.x;
  int e = tid >> 4;
  if (e >= NE) return;
  int q = tid & 15;
  int sv = src[e];
  int dv = dst[e];
  float4 v = reinterpret_cast<const float4*>(x + (size_t)sv * DD)[q];
  float* o = s + (size_t)dv * DD + q * 4;
  atomicAdd(o + 0, v.x);
  atomicAdd(o + 1, v.y);
  atomicAdd(o + 2, v.z);
  atomicAdd(o + 3, v.w);
  if (do_cnt && q == 0) atomicAdd(cnt + dv, 1.0f);
}

// ---------------- fused SAGE update ----------------
// out[n][j] = relu?( (x[n]@wl.T + bl + (s[n]/max(cnt,1))@wr.T + br) / max(||.||2, eps) )
// block = 256 threads = 4 nodes x 64 lanes (one wave per node).
// Weights staged transposed in LDS as float2 (wl, wr) -> per k: 1 broadcast
// b64 read + 1 consecutive b64 read + 2 FMA. No bank conflicts.
__launch_bounds__(256)
__global__ void sage_kernel(const float* __restrict__ x,
                            const float* __restrict__ s,
                            const float* __restrict__ cnt,
                            const float* __restrict__ wl,
                            const float* __restrict__ bl,
                            const float* __restrict__ wr,
                            const float* __restrict__ br,
                            float* __restrict__ out,
                            int relu) {
  __shared__ float2 wlds[DD * DD];   // [k][j] = (wl[j][k], wr[j][k])
  __shared__ float2 xp[4][DD];       // per-group staged (x, prop)
  int tid = threadIdx.x;
  int j = tid & 63;
  int g = tid >> 6;

  for (int i = tid; i < DD * DD; i += 256) {
    int jj = i >> 6, kk = i & 63;    // coalesced global read, transposed LDS write
    wlds[kk * DD + jj] = make_float2(wl[i], wr[i]);
  }
  float bias = bl[j] + br[j];
  __syncthreads();

  const int ngroups = (NN + 3) / 4;
  for (int grp = blockIdx.x; grp < ngroups; grp += gridDim.x) {
    int n = grp * 4 + g;
    if (n < NN) {
      float rc = 1.0f / fmaxf(cnt[n], 1.0f);
      xp[g][j] = make_float2(x[(size_t)n * DD + j], s[(size_t)n * DD + j] * rc);
    }
    __syncthreads();
    if (n < NN) {
      float acc = bias;
      #pragma unroll
      for (int k = 0; k < DD; ++k) {
        float2 v = xp[g][k];
        float2 w = wlds[k * DD + j];
        acc = fmaf(v.x, w.x, acc);
        acc = fmaf(v.y, w.y, acc);
      }
      // row L2 norm across the 64 lanes of this wave
      float ss = acc * acc;
      #pragma unroll
      for (int off = 32; off > 0; off >>= 1) ss += __shfl_xor(ss, off, 64);
      float o = acc / fmaxf(sqrtf(ss), 1e-12f);
      if (relu) o = fmaxf(o, 0.0f);
      out[(size_t)n * DD + j] = o;
    }
    __syncthreads();
  }
}

// ---------------- fused post-MLP: h@w1.T+b1 -> @w2.T+b2 ----------------
__launch_bounds__(256)
__global__ void post_kernel(const float* __restrict__ h,
                            const float* __restrict__ w1,
                            const float* __restrict__ b1,
                            const float* __restrict__ w2,
                            const float* __restrict__ b2,
                            float* __restrict__ out) {
  __shared__ float2 wds[DD * DD];    // [k][j] = (w1[j][k], w2[j][k])
  __shared__ float hs[4][DD];
  __shared__ float ts[4][DD];
  int tid = threadIdx.x;
  int j = tid & 63;
  int g = tid >> 6;

  for (int i = tid; i < DD * DD; i += 256) {
    int jj = i >> 6, kk = i & 63;
    wds[kk * DD + jj] = make_float2(w1[i], w2[i]);
  }
  float bb1 = b1[j];
  float bb2 = b2[j];
  __syncthreads();

  const int ngroups = (NN + 3) / 4;
  for (int grp = blockIdx.x; grp < ngroups; grp += gridDim.x) {
    int n = grp * 4 + g;
    if (n < NN) hs[g][j] = h[(size_t)n * DD + j];
    __syncthreads();
    if (n < NN) {
      float acc1 = bb1;
      #pragma unroll
      for (int k = 0; k < DD; ++k) acc1 = fmaf(hs[g][k], wds[k * DD + j].x, acc1);
      ts[g][j] = acc1;
    }
    __syncthreads();
    if (n < NN) {
      float acc2 = bb2;
      #pragma unroll
      for (int k = 0; k < DD; ++k) acc2 = fmaf(ts[g][k], wds[k * DD + j].y, acc2);
      out[(size_t)n * DD + j] = acc2;
    }
    __syncthreads();
  }
}

extern "C" void kernel_launch(void* const* d_in, const int* in_sizes, int n_in,
                              void* d_out, int out_size, void* d_ws, size_t ws_size,
                              hipStream_t stream) {
  const float* x   = (const float*)d_in[0];
  const int*   ei  = (const int*)d_in[1];
  const float* w1l = (const float*)d_in[2];
  const float* b1l = (const float*)d_in[3];
  const float* w1r = (const float*)d_in[4];
  const float* b1r = (const float*)d_in[5];
  const float* w2l = (const float*)d_in[6];
  const float* b2l = (const float*)d_in[7];
  const float* w2r = (const float*)d_in[8];
  const float* b2r = (const float*)d_in[9];
  const float* wp1 = (const float*)d_in[10];
  const float* bp1 = (const float*)d_in[11];
  const float* wp2 = (const float*)d_in[12];
  const float* bp2 = (const float*)d_in[13];
  float* out = (float*)d_out;

  const int* src = ei;
  const int* dst = ei + NE;

  // workspace layout: cnt (padded to 102400 floats) | s (N*D) | h (N*D)
  float* cnt = (float*)d_ws;
  float* s   = cnt + 102400;
  float* h   = s + NN * DD;

  const int scatter_blocks = (NE * 16) / 256;  // 100000
  const int gemm_blocks = 1024;

  // layer 1
  zero_kernel<<<2048, 256, 0, stream>>>(cnt, 102400 + NN * DD);  // cnt + s contiguous
  scatter_kernel<<<scatter_blocks, 256, 0, stream>>>(x, src, dst, s, cnt, 1);
  sage_kernel<<<gemm_blocks, 256, 0, stream>>>(x, s, cnt, w1l, b1l, w1r, b1r, h, 1);

  // layer 2 (cnt reused; aggregation in-place into s)
  zero_kernel<<<2048, 256, 0, stream>>>(s, NN * DD);
  scatter_kernel<<<scatter_blocks, 256, 0, stream>>>(h, src, dst, s, cnt, 0);
  sage_kernel<<<gemm_blocks, 256, 0, stream>>>(h, s, cnt, w2l, b2l, w2r, b2r, h, 1);

  // post-MLP
  post_kernel<<<gemm_blocks, 256, 0, stream>>>(h, wp1, bp1, wp2, bp2, out);
}

// Round 2
// 612.745 us; speedup vs baseline: 5.0824x; 5.0824x over previous
//
#include <hip/hip_runtime.h>

#define NN 100000
#define NE 1600000
#define DD 64
#define SCAN_BS 256
#define NBLK ((NN + SCAN_BS - 1) / SCAN_BS)   // 391

// ---------------- zero ----------------
__global__ void zero_kernel(int* __restrict__ p, int n) {
  int i = blockIdx.x * blockDim.x + threadIdx.x;
  int stride = gridDim.x * blockDim.x;
  for (; i < n; i += stride) p[i] = 0;
}

// ---------------- degree histogram ----------------
__global__ void hist_kernel(const int* __restrict__ dst, int* __restrict__ deg) {
  int e = blockIdx.x * 256 + threadIdx.x;
  if (e < NE) atomicAdd(&deg[dst[e]], 1);
}

// ---------------- scan stage 1: per-block exclusive scan ----------------
__global__ void scan1_kernel(const int* __restrict__ deg, int* __restrict__ off,
                             int* __restrict__ bsum) {
  __shared__ int wsum[4];
  int i = blockIdx.x * SCAN_BS + threadIdx.x;
  int lane = threadIdx.x & 63, g = threadIdx.x >> 6;
  int v = (i < NN) ? deg[i] : 0;
  int incl = v;
  #pragma unroll
  for (int o = 1; o < 64; o <<= 1) {
    int t = __shfl_up(incl, o, 64);
    if (lane >= o) incl += t;
  }
  if (lane == 63) wsum[g] = incl;
  __syncthreads();
  int prefix = 0;
  for (int w = 0; w < g; ++w) prefix += wsum[w];
  if (i < NN) off[i] = prefix + incl - v;
  if (threadIdx.x == SCAN_BS - 1) bsum[blockIdx.x] = prefix + incl;
}

// ---------------- scan stage 2: scan of block sums (1 block) ----------------
__global__ void scan2_kernel(int* __restrict__ bsum) {
  __shared__ int tmp[512];
  int i = threadIdx.x;
  int v = (i < NBLK) ? bsum[i] : 0;
  tmp[i] = v;
  __syncthreads();
  for (int o = 1; o < 512; o <<= 1) {
    int t = (i >= o) ? tmp[i - o] : 0;
    __syncthreads();
    tmp[i] += t;
    __syncthreads();
  }
  if (i < NBLK) bsum[i] = tmp[i] - v;   // exclusive
}

// ---------------- scan stage 3: add block offsets ----------------
__global__ void scan3_kernel(int* __restrict__ off, const int* __restrict__ bsum) {
  int i = blockIdx.x * SCAN_BS + threadIdx.x;
  if (i < NN) off[i] += bsum[blockIdx.x];
}

// ---------------- CSR fill ----------------
__global__ void fill_kernel(const int* __restrict__ src, const int* __restrict__ dst,
                            const int* __restrict__ off, int* __restrict__ cur,
                            int* __restrict__ adj) {
  int e = blockIdx.x * 256 + threadIdx.x;
  if (e >= NE) return;
  int d = dst[e];
  int pos = off[d] + atomicAdd(&cur[d], 1);
  adj[pos] = src[e];
}

// ---------------- fused SAGE: gather-mean + dual GEMM + L2norm + relu ----------------
// block = 256 = 4 waves; each wave owns one node per group iteration.
// Gather: lane j accumulates feature j over neighbor rows (256B coalesced reads).
__launch_bounds__(256)
__global__ void sage_kernel(const float* __restrict__ x,
                            const int* __restrict__ off,
                            const int* __restrict__ deg,
                            const int* __restrict__ adj,
                            const float* __restrict__ wl,
                            const float* __restrict__ bl,
                            const float* __restrict__ wr,
                            const float* __restrict__ br,
                            float* __restrict__ out,
                            int relu) {
  __shared__ float2 wlds[DD * DD];   // [k][j] = (wl[j][k], wr[j][k])
  __shared__ float2 xp[4][DD];       // per-wave staged (self, prop)
  int tid = threadIdx.x;
  int j = tid & 63;
  int g = tid >> 6;

  for (int i = tid; i < DD * DD; i += 256) {
    int jj = i >> 6, kk = i & 63;    // coalesced read, transposed LDS write
    wlds[kk * DD + jj] = make_float2(wl[i], wr[i]);
  }
  float bias = bl[j] + br[j];
  __syncthreads();

  const int ngroups = (NN + 3) / 4;
  for (int grp = blockIdx.x; grp < ngroups; grp += gridDim.x) {
    int n = grp * 4 + g;
    if (n < NN) {
      int start = off[n];
      int dcount = deg[n];
      float a0 = 0.f, a1 = 0.f, a2 = 0.f, a3 = 0.f;
      int t = 0;
      for (; t + 4 <= dcount; t += 4) {
        int s0 = adj[start + t + 0];
        int s1 = adj[start + t + 1];
        int s2 = adj[start + t + 2];
        int s3 = adj[start + t + 3];
        a0 += x[(size_t)s0 * DD + j];
        a1 += x[(size_t)s1 * DD + j];
        a2 += x[(size_t)s2 * DD + j];
        a3 += x[(size_t)s3 * DD + j];
      }
      for (; t < dcount; ++t) a0 += x[(size_t)adj[start + t] * DD + j];
      float sumv = (a0 + a1) + (a2 + a3);
      float rc = 1.0f / fmaxf((float)dcount, 1.0f);
      xp[g][j] = make_float2(x[(size_t)n * DD + j], sumv * rc);
    }
    __syncthreads();
    if (n < NN) {
      float acc = bias;
      #pragma unroll
      for (int k = 0; k < DD; ++k) {
        float2 v = xp[g][k];
        float2 w = wlds[k * DD + j];
        acc = fmaf(v.x, w.x, acc);
        acc = fmaf(v.y, w.y, acc);
      }
      float ss = acc * acc;
      #pragma unroll
      for (int o = 32; o > 0; o >>= 1) ss += __shfl_xor(ss, o, 64);
      float ov = acc / fmaxf(sqrtf(ss), 1e-12f);
      if (relu) ov = fmaxf(ov, 0.0f);
      out[(size_t)n * DD + j] = ov;
    }
    __syncthreads();
  }
}

// ---------------- fused post-MLP (row-local, safe in-place) ----------------
__launch_bounds__(256)
__global__ void post_kernel(const float* __restrict__ h,
                            const float* __restrict__ w1,
                            const float* __restrict__ b1,
                            const float* __restrict__ w2,
                            const float* __restrict__ b2,
                            float* __restrict__ out) {
  __shared__ float2 wds[DD * DD];    // [k][j] = (w1[j][k], w2[j][k])
  __shared__ float hs[4][DD];
  __shared__ float ts[4][DD];
  int tid = threadIdx.x;
  int j = tid & 63;
  int g = tid >> 6;

  for (int i = tid; i < DD * DD; i += 256) {
    int jj = i >> 6, kk = i & 63;
    wds[kk * DD + jj] = make_float2(w1[i], w2[i]);
  }
  float bb1 = b1[j];
  float bb2 = b2[j];
  __syncthreads();

  const int ngroups = (NN + 3) / 4;
  for (int grp = blockIdx.x; grp < ngroups; grp += gridDim.x) {
    int n = grp * 4 + g;
    if (n < NN) hs[g][j] = h[(size_t)n * DD + j];
    __syncthreads();
    if (n < NN) {
      float acc1 = bb1;
      #pragma unroll
      for (int k = 0; k < DD; ++k) acc1 = fmaf(hs[g][k], wds[k * DD + j].x, acc1);
      ts[g][j] = acc1;
    }
    __syncthreads();
    if (n < NN) {
      float acc2 = bb2;
      #pragma unroll
      for (int k = 0; k < DD; ++k) acc2 = fmaf(ts[g][k], wds[k * DD + j].y, acc2);
      out[(size_t)n * DD + j] = acc2;
    }
    __syncthreads();
  }
}

extern "C" void kernel_launch(void* const* d_in, const int* in_sizes, int n_in,
                              void* d_out, int out_size, void* d_ws, size_t ws_size,
                              hipStream_t stream) {
  const float* x   = (const float*)d_in[0];
  const int*   ei  = (const int*)d_in[1];
  const float* w1l = (const float*)d_in[2];
  const float* b1l = (const float*)d_in[3];
  const float* w1r = (const float*)d_in[4];
  const float* b1r = (const float*)d_in[5];
  const float* w2l = (const float*)d_in[6];
  const float* b2l = (const float*)d_in[7];
  const float* w2r = (const float*)d_in[8];
  const float* b2r = (const float*)d_in[9];
  const float* wp1 = (const float*)d_in[10];
  const float* bp1 = (const float*)d_in[11];
  const float* wp2 = (const float*)d_in[12];
  const float* bp2 = (const float*)d_in[13];
  float* out = (float*)d_out;

  const int* src = ei;
  const int* dst = ei + NE;

  // workspace layout (4B units):
  // deg[102400] | cur[102400] | off[102400] | bsum[1024] | adj[NE] | h[NN*DD]
  int* deg  = (int*)d_ws;
  int* cur  = deg + 102400;
  int* off  = cur + 102400;
  int* bsum = off + 102400;
  int* adj  = bsum + 1024;
  float* h  = (float*)(adj + NE);

  const int egrid = (NE + 255) / 256;       // 6250
  const int gemm_blocks = 2048;

  // ---- build CSR (deg, off, adj) once; reused by both layers ----
  zero_kernel<<<512, 256, 0, stream>>>(deg, 204800);            // deg + cur contiguous
  hist_kernel<<<egrid, 256, 0, stream>>>(dst, deg);
  scan1_kernel<<<NBLK, SCAN_BS, 0, stream>>>(deg, off, bsum);
  scan2_kernel<<<1, 512, 0, stream>>>(bsum);
  scan3_kernel<<<NBLK, SCAN_BS, 0, stream>>>(off, bsum);
  fill_kernel<<<egrid, 256, 0, stream>>>(src, dst, off, cur, adj);

  // ---- layer 1: x -> h ----
  sage_kernel<<<gemm_blocks, 256, 0, stream>>>(x, off, deg, adj, w1l, b1l, w1r, b1r, h, 1);
  // ---- layer 2: h -> out (temp) ----
  sage_kernel<<<gemm_blocks, 256, 0, stream>>>(h, off, deg, adj, w2l, b2l, w2r, b2r, out, 1);
  // ---- post-MLP: out -> out (row-local in-place) ----
  post_kernel<<<gemm_blocks, 256, 0, stream>>>(out, wp1, bp1, wp2, bp2, out);
}

// Round 3
// 463.700 us; speedup vs baseline: 6.7160x; 1.3214x over previous
//
#include <hip/hip_runtime.h>

#define NN 100000
#define NE 1600000
#define DD 64
#define SCAN_BS 256
#define NBLK ((NN + SCAN_BS - 1) / SCAN_BS)   // 391

// ---------------- zero ----------------
__global__ void zero_kernel(int* __restrict__ p, int n) {
  int i = blockIdx.x * blockDim.x + threadIdx.x;
  int stride = gridDim.x * blockDim.x;
  for (; i < n; i += stride) p[i] = 0;
}

// ---------------- degree histogram (int4 edges) ----------------
__global__ void hist_kernel(const int* __restrict__ dst, int* __restrict__ deg) {
  int e4 = blockIdx.x * 256 + threadIdx.x;
  if (e4 >= NE / 4) return;
  int4 d = reinterpret_cast<const int4*>(dst)[e4];
  atomicAdd(&deg[d.x], 1);
  atomicAdd(&deg[d.y], 1);
  atomicAdd(&deg[d.z], 1);
  atomicAdd(&deg[d.w], 1);
}

// ---------------- scan stage 1: per-block exclusive scan ----------------
__global__ void scan1_kernel(const int* __restrict__ deg, int* __restrict__ off,
                             int* __restrict__ bsum) {
  __shared__ int wsum[4];
  int i = blockIdx.x * SCAN_BS + threadIdx.x;
  int lane = threadIdx.x & 63, g = threadIdx.x >> 6;
  int v = (i < NN) ? deg[i] : 0;
  int incl = v;
  #pragma unroll
  for (int o = 1; o < 64; o <<= 1) {
    int t = __shfl_up(incl, o, 64);
    if (lane >= o) incl += t;
  }
  if (lane == 63) wsum[g] = incl;
  __syncthreads();
  int prefix = 0;
  for (int w = 0; w < g; ++w) prefix += wsum[w];
  if (i < NN) off[i] = prefix + incl - v;
  if (threadIdx.x == SCAN_BS - 1) bsum[blockIdx.x] = prefix + incl;
}

// ---------------- scan stage 2: scan of block sums (1 block) ----------------
__global__ void scan2_kernel(int* __restrict__ bsum) {
  __shared__ int tmp[512];
  int i = threadIdx.x;
  int v = (i < NBLK) ? bsum[i] : 0;
  tmp[i] = v;
  __syncthreads();
  for (int o = 1; o < 512; o <<= 1) {
    int t = (i >= o) ? tmp[i - o] : 0;
    __syncthreads();
    tmp[i] += t;
    __syncthreads();
  }
  if (i < NBLK) bsum[i] = tmp[i] - v;   // exclusive
}

// ---------------- scan stage 3: add block offsets ----------------
__global__ void scan3_kernel(int* __restrict__ off, const int* __restrict__ bsum) {
  int i = blockIdx.x * SCAN_BS + threadIdx.x;
  if (i < NN) off[i] += bsum[blockIdx.x];
}

// ---------------- CSR fill (int4 edges) ----------------
__global__ void fill_kernel(const int* __restrict__ src, const int* __restrict__ dst,
                            const int* __restrict__ off, int* __restrict__ cur,
                            int* __restrict__ adj) {
  int e4 = blockIdx.x * 256 + threadIdx.x;
  if (e4 >= NE / 4) return;
  int4 d = reinterpret_cast<const int4*>(dst)[e4];
  int4 s = reinterpret_cast<const int4*>(src)[e4];
  adj[off[d.x] + atomicAdd(&cur[d.x], 1)] = s.x;
  adj[off[d.y] + atomicAdd(&cur[d.y], 1)] = s.y;
  adj[off[d.z] + atomicAdd(&cur[d.z], 1)] = s.z;
  adj[off[d.w] + atomicAdd(&cur[d.w], 1)] = s.w;
}

// ---------------- fused SAGE: gather-mean + dual GEMM + L2norm + relu ----------
// block = 512 = 8 waves. Each wave owns a QUAD of 4 nodes (no inter-wave
// sharing -> no syncthreads in the loop). Weight LDS reads amortized x4.
// 25000 quads = 3125 groups x 8 waves exactly -> no bounds checks.
__launch_bounds__(512)
__global__ void sage_kernel(const float* __restrict__ x,
                            const int* __restrict__ off,
                            const int* __restrict__ deg,
                            const int* __restrict__ adj,
                            const float* __restrict__ wl,
                            const float* __restrict__ bl,
                            const float* __restrict__ wr,
                            const float* __restrict__ br,
                            float* __restrict__ out,
                            int relu) {
  __shared__ float wlA[DD * DD];      // [k][j] = wl[j][k]   16KB
  __shared__ float wrA[DD * DD];      // [k][j] = wr[j][k]   16KB
  __shared__ float2 xp[8][4][DD];     // (self, prop) per wave-quad  16KB
  int tid = threadIdx.x;
  int j = tid & 63;
  int w = tid >> 6;

  for (int i = tid; i < DD * DD; i += 512) {
    int jj = i >> 6, kk = i & 63;     // coalesced global read, transposed LDS write
    wlA[kk * DD + jj] = wl[i];
    wrA[kk * DD + jj] = wr[i];
  }
  float bias = bl[j] + br[j];
  __syncthreads();                    // only sync: weights ready

  const int ngrp = 3125;              // 25000 quads / 8 waves
  for (int grp = blockIdx.x; grp < ngrp; grp += gridDim.x) {
    int n0 = (grp * 8 + w) * 4;

    // ---- gather-mean + stage 4 nodes (wave-local, no sync) ----
    for (int i = 0; i < 4; ++i) {
      int n = n0 + i;
      int start = __builtin_amdgcn_readfirstlane(off[n]);
      int d     = __builtin_amdgcn_readfirstlane(deg[n]);
      float a0 = 0.f, a1 = 0.f, a2 = 0.f, a3 = 0.f;
      int t = 0;
      for (; t + 4 <= d; t += 4) {
        int s0 = adj[start + t + 0];
        int s1 = adj[start + t + 1];
        int s2 = adj[start + t + 2];
        int s3 = adj[start + t + 3];
        a0 += x[(size_t)s0 * DD + j];
        a1 += x[(size_t)s1 * DD + j];
        a2 += x[(size_t)s2 * DD + j];
        a3 += x[(size_t)s3 * DD + j];
      }
      for (; t < d; ++t) a0 += x[(size_t)adj[start + t] * DD + j];
      float sum = (a0 + a1) + (a2 + a3);
      float rc = 1.0f / fmaxf((float)d, 1.0f);
      xp[w][i][j] = make_float2(x[(size_t)n * DD + j], sum * rc);
    }

    // ---- quad GEMM: weight read amortized over 4 nodes ----
    float acc0 = bias, acc1 = bias, acc2 = bias, acc3 = bias;
    #pragma unroll
    for (int k = 0; k < DD; ++k) {
      float wlk = wlA[k * DD + j];
      float wrk = wrA[k * DD + j];
      float2 v0 = xp[w][0][k];
      float2 v1 = xp[w][1][k];
      float2 v2 = xp[w][2][k];
      float2 v3 = xp[w][3][k];
      acc0 = fmaf(v0.x, wlk, fmaf(v0.y, wrk, acc0));
      acc1 = fmaf(v1.x, wlk, fmaf(v1.y, wrk, acc1));
      acc2 = fmaf(v2.x, wlk, fmaf(v2.y, wrk, acc2));
      acc3 = fmaf(v3.x, wlk, fmaf(v3.y, wrk, acc3));
    }

    // ---- per-node L2 normalize + relu + store ----
    #pragma unroll
    for (int i = 0; i < 4; ++i) {
      float acc = (i == 0) ? acc0 : (i == 1) ? acc1 : (i == 2) ? acc2 : acc3;
      float ss = acc * acc;
      #pragma unroll
      for (int o = 32; o > 0; o >>= 1) ss += __shfl_xor(ss, o, 64);
      float ov = acc / fmaxf(sqrtf(ss), 1e-12f);
      if (relu) ov = fmaxf(ov, 0.0f);
      out[(size_t)(n0 + i) * DD + j] = ov;
    }
  }
}

// ---------------- fused post-MLP, quad-batched (row-local, in-place safe) ----
__launch_bounds__(512)
__global__ void post_kernel(const float* __restrict__ h,
                            const float* __restrict__ w1,
                            const float* __restrict__ b1,
                            const float* __restrict__ w2,
                            const float* __restrict__ b2,
                            float* __restrict__ out) {
  __shared__ float w1A[DD * DD];      // [k][j] = w1[j][k]
  __shared__ float w2A[DD * DD];      // [k][j] = w2[j][k]
  __shared__ float hp[8][4][DD];
  __shared__ float tp[8][4][DD];
  int tid = threadIdx.x;
  int j = tid & 63;
  int w = tid >> 6;

  for (int i = tid; i < DD * DD; i += 512) {
    int jj = i >> 6, kk = i & 63;
    w1A[kk * DD + jj] = w1[i];
    w2A[kk * DD + jj] = w2[i];
  }
  float bb1 = b1[j];
  float bb2 = b2[j];
  __syncthreads();

  const int ngrp = 3125;
  for (int grp = blockIdx.x; grp < ngrp; grp += gridDim.x) {
    int n0 = (grp * 8 + w) * 4;
    #pragma unroll
    for (int i = 0; i < 4; ++i) hp[w][i][j] = h[(size_t)(n0 + i) * DD + j];

    float a0 = bb1, a1 = bb1, a2 = bb1, a3 = bb1;
    #pragma unroll
    for (int k = 0; k < DD; ++k) {
      float wk = w1A[k * DD + j];
      a0 = fmaf(hp[w][0][k], wk, a0);
      a1 = fmaf(hp[w][1][k], wk, a1);
      a2 = fmaf(hp[w][2][k], wk, a2);
      a3 = fmaf(hp[w][3][k], wk, a3);
    }
    tp[w][0][j] = a0; tp[w][1][j] = a1; tp[w][2][j] = a2; tp[w][3][j] = a3;

    float c0 = bb2, c1 = bb2, c2 = bb2, c3 = bb2;
    #pragma unroll
    for (int k = 0; k < DD; ++k) {
      float wk = w2A[k * DD + j];
      c0 = fmaf(tp[w][0][k], wk, c0);
      c1 = fmaf(tp[w][1][k], wk, c1);
      c2 = fmaf(tp[w][2][k], wk, c2);
      c3 = fmaf(tp[w][3][k], wk, c3);
    }
    out[(size_t)(n0 + 0) * DD + j] = c0;
    out[(size_t)(n0 + 1) * DD + j] = c1;
    out[(size_t)(n0 + 2) * DD + j] = c2;
    out[(size_t)(n0 + 3) * DD + j] = c3;
  }
}

extern "C" void kernel_launch(void* const* d_in, const int* in_sizes, int n_in,
                              void* d_out, int out_size, void* d_ws, size_t ws_size,
                              hipStream_t stream) {
  const float* x   = (const float*)d_in[0];
  const int*   ei  = (const int*)d_in[1];
  const float* w1l = (const float*)d_in[2];
  const float* b1l = (const float*)d_in[3];
  const float* w1r = (const float*)d_in[4];
  const float* b1r = (const float*)d_in[5];
  const float* w2l = (const float*)d_in[6];
  const float* b2l = (const float*)d_in[7];
  const float* w2r = (const float*)d_in[8];
  const float* b2r = (const float*)d_in[9];
  const float* wp1 = (const float*)d_in[10];
  const float* bp1 = (const float*)d_in[11];
  const float* wp2 = (const float*)d_in[12];
  const float* bp2 = (const float*)d_in[13];
  float* out = (float*)d_out;

  const int* src = ei;
  const int* dst = ei + NE;

  // workspace (4B units): deg[102400] | cur[102400] | off[102400] | bsum[1024]
  //                      | adj[NE] | h[NN*DD]
  int* deg  = (int*)d_ws;
  int* cur  = deg + 102400;
  int* off  = cur + 102400;
  int* bsum = off + 102400;
  int* adj  = bsum + 1024;
  float* h  = (float*)(adj + NE);

  const int e4grid = (NE / 4 + 255) / 256;   // 1563

  // ---- build CSR once (reused by both layers) ----
  zero_kernel<<<512, 256, 0, stream>>>(deg, 204800);            // deg + cur
  hist_kernel<<<e4grid, 256, 0, stream>>>(dst, deg);
  scan1_kernel<<<NBLK, SCAN_BS, 0, stream>>>(deg, off, bsum);
  scan2_kernel<<<1, 512, 0, stream>>>(bsum);
  scan3_kernel<<<NBLK, SCAN_BS, 0, stream>>>(off, bsum);
  fill_kernel<<<e4grid, 256, 0, stream>>>(src, dst, off, cur, adj);

  // ---- layer 1: x -> h ----
  sage_kernel<<<768, 512, 0, stream>>>(x, off, deg, adj, w1l, b1l, w1r, b1r, h, 1);
  // ---- layer 2: h -> out ----
  sage_kernel<<<768, 512, 0, stream>>>(h, off, deg, adj, w2l, b2l, w2r, b2r, out, 1);
  // ---- post-MLP in-place on out ----
  post_kernel<<<768, 512, 0, stream>>>(out, wp1, bp1, wp2, bp2, out);
}

// Round 4
// 428.766 us; speedup vs baseline: 7.2632x; 1.0815x over previous
//
#include <hip/hip_runtime.h>

#define NN 100000
#define NE 1600000
#define DD 64
#define NOCT 12500                         // NN / 8 nodes-per-wave
#define SCAN_BS 256
#define NBLK ((NN + SCAN_BS - 1) / SCAN_BS)   // 391

// ---------------- zero ----------------
__global__ void zero_kernel(int* __restrict__ p, int n) {
  int i = blockIdx.x * blockDim.x + threadIdx.x;
  int stride = gridDim.x * blockDim.x;
  for (; i < n; i += stride) p[i] = 0;
}

// ---------------- degree histogram (int4 edges) ----------------
__global__ void hist_kernel(const int* __restrict__ dst, int* __restrict__ deg) {
  int e4 = blockIdx.x * 256 + threadIdx.x;
  if (e4 >= NE / 4) return;
  int4 d = reinterpret_cast<const int4*>(dst)[e4];
  atomicAdd(&deg[d.x], 1);
  atomicAdd(&deg[d.y], 1);
  atomicAdd(&deg[d.z], 1);
  atomicAdd(&deg[d.w], 1);
}

// ---------------- scan stage 1 ----------------
__global__ void scan1_kernel(const int* __restrict__ deg, int* __restrict__ off,
                             int* __restrict__ bsum) {
  __shared__ int wsum[4];
  int i = blockIdx.x * SCAN_BS + threadIdx.x;
  int lane = threadIdx.x & 63, g = threadIdx.x >> 6;
  int v = (i < NN) ? deg[i] : 0;
  int incl = v;
  #pragma unroll
  for (int o = 1; o < 64; o <<= 1) {
    int t = __shfl_up(incl, o, 64);
    if (lane >= o) incl += t;
  }
  if (lane == 63) wsum[g] = incl;
  __syncthreads();
  int prefix = 0;
  for (int w = 0; w < g; ++w) prefix += wsum[w];
  if (i < NN) off[i] = prefix + incl - v;
  if (threadIdx.x == SCAN_BS - 1) bsum[blockIdx.x] = prefix + incl;
}

// ---------------- scan stage 2 ----------------
__global__ void scan2_kernel(int* __restrict__ bsum) {
  __shared__ int tmp[512];
  int i = threadIdx.x;
  int v = (i < NBLK) ? bsum[i] : 0;
  tmp[i] = v;
  __syncthreads();
  for (int o = 1; o < 512; o <<= 1) {
    int t = (i >= o) ? tmp[i - o] : 0;
    __syncthreads();
    tmp[i] += t;
    __syncthreads();
  }
  if (i < NBLK) bsum[i] = tmp[i] - v;
}

// ---------------- scan stage 3 ----------------
__global__ void scan3_kernel(int* __restrict__ off, const int* __restrict__ bsum) {
  int i = blockIdx.x * SCAN_BS + threadIdx.x;
  if (i < NN) off[i] += bsum[blockIdx.x];
}

// ---------------- CSR fill (int4 edges) ----------------
__global__ void fill_kernel(const int* __restrict__ src, const int* __restrict__ dst,
                            const int* __restrict__ off, int* __restrict__ cur,
                            int* __restrict__ adj) {
  int e4 = blockIdx.x * 256 + threadIdx.x;
  if (e4 >= NE / 4) return;
  int4 d = reinterpret_cast<const int4*>(dst)[e4];
  int4 s = reinterpret_cast<const int4*>(src)[e4];
  adj[off[d.x] + atomicAdd(&cur[d.x], 1)] = s.x;
  adj[off[d.y] + atomicAdd(&cur[d.y], 1)] = s.y;
  adj[off[d.z] + atomicAdd(&cur[d.z], 1)] = s.z;
  adj[off[d.w] + atomicAdd(&cur[d.w], 1)] = s.w;
}

// ---------------- fused SAGE: gather-mean + dual GEMM + L2norm + relu ----------
// block = 512 = 8 waves; each wave owns 8 nodes (an "oct"); no in-loop syncs.
// LDS = weights [k][j] 32KB + sp/pp (self, prop) 32KB = 64KB -> 2 blocks/CU.
// GEMM: per k-quad, 8 per-lane weight b32 reads (conflict-free) + per node
// two float4 same-address broadcasts (free) -> DS-pipe traffic cut ~4x.
__launch_bounds__(512, 4)
__global__ void sage_kernel(const float* __restrict__ x,
                            const int* __restrict__ off,
                            const int* __restrict__ deg,
                            const int* __restrict__ adj,
                            const float* __restrict__ wl,
                            const float* __restrict__ bl,
                            const float* __restrict__ wr,
                            const float* __restrict__ br,
                            float* __restrict__ out,
                            int relu) {
  __shared__ float wlA[DD * DD] __attribute__((aligned(16)));  // [k][j]
  __shared__ float wrA[DD * DD] __attribute__((aligned(16)));  // [k][j]
  __shared__ float sp[8][8][DD] __attribute__((aligned(16)));  // self rows
  __shared__ float pp[8][8][DD] __attribute__((aligned(16)));  // prop rows
  int tid = threadIdx.x;
  int j = tid & 63;
  int w = tid >> 6;

  for (int i = tid; i < DD * DD; i += 512) {
    int jj = i >> 6, kk = i & 63;     // coalesced global read, transposed write
    wlA[kk * DD + jj] = wl[i];
    wrA[kk * DD + jj] = wr[i];
  }
  float bias = bl[j] + br[j];
  __syncthreads();                    // only sync: weights ready

  const int ngrp = (NOCT + 7) / 8;   // 1563
  for (int grp = blockIdx.x; grp < ngrp; grp += gridDim.x) {
    int o = grp * 8 + w;
    if (o >= NOCT) continue;
    int n0 = o * 8;

    // ---- gather-mean + stage 8 nodes (wave-local; 8 loads in flight) ----
    for (int i = 0; i < 8; ++i) {
      int n = n0 + i;
      int start = __builtin_amdgcn_readfirstlane(off[n]);
      int d     = __builtin_amdgcn_readfirstlane(deg[n]);
      float selfv = x[(size_t)n * DD + j];
      float a0 = 0.f, a1 = 0.f, a2 = 0.f, a3 = 0.f;
      float a4 = 0.f, a5 = 0.f, a6 = 0.f, a7 = 0.f;
      int t = 0;
      for (; t + 8 <= d; t += 8) {
        int s0 = adj[start + t + 0];
        int s1 = adj[start + t + 1];
        int s2 = adj[start + t + 2];
        int s3 = adj[start + t + 3];
        int s4 = adj[start + t + 4];
        int s5 = adj[start + t + 5];
        int s6 = adj[start + t + 6];
        int s7 = adj[start + t + 7];
        a0 += x[(size_t)s0 * DD + j];
        a1 += x[(size_t)s1 * DD + j];
        a2 += x[(size_t)s2 * DD + j];
        a3 += x[(size_t)s3 * DD + j];
        a4 += x[(size_t)s4 * DD + j];
        a5 += x[(size_t)s5 * DD + j];
        a6 += x[(size_t)s6 * DD + j];
        a7 += x[(size_t)s7 * DD + j];
      }
      if (t < d) {                    // uniform masked tail (<=7 rows)
        int dm = d - 1;
        int u1 = (t + 1 < d) ? t + 1 : dm;
        int u2 = (t + 2 < d) ? t + 2 : dm;
        int u3 = (t + 3 < d) ? t + 3 : dm;
        int u4 = (t + 4 < d) ? t + 4 : dm;
        int u5 = (t + 5 < d) ? t + 5 : dm;
        int u6 = (t + 6 < d) ? t + 6 : dm;
        int s0 = adj[start + t];
        int s1 = adj[start + u1];
        int s2 = adj[start + u2];
        int s3 = adj[start + u3];
        int s4 = adj[start + u4];
        int s5 = adj[start + u5];
        int s6 = adj[start + u6];
        float v0 = x[(size_t)s0 * DD + j];
        float v1 = x[(size_t)s1 * DD + j];
        float v2 = x[(size_t)s2 * DD + j];
        float v3 = x[(size_t)s3 * DD + j];
        float v4 = x[(size_t)s4 * DD + j];
        float v5 = x[(size_t)s5 * DD + j];
        float v6 = x[(size_t)s6 * DD + j];
        a0 += v0;
        a1 += (t + 1 < d) ? v1 : 0.f;
        a2 += (t + 2 < d) ? v2 : 0.f;
        a3 += (t + 3 < d) ? v3 : 0.f;
        a4 += (t + 4 < d) ? v4 : 0.f;
        a5 += (t + 5 < d) ? v5 : 0.f;
        a6 += (t + 6 < d) ? v6 : 0.f;
      }
      float sum = ((a0 + a1) + (a2 + a3)) + ((a4 + a5) + (a6 + a7));
      float rc = 1.0f / fmaxf((float)d, 1.0f);
      sp[w][i][j] = selfv;
      pp[w][i][j] = sum * rc;
    }

    // ---- GEMM: 8 nodes, weights amortized, float4 broadcasts ----
    float acc[8];
    #pragma unroll
    for (int i = 0; i < 8; ++i) acc[i] = bias;

    #pragma unroll
    for (int q = 0; q < 16; ++q) {
      int kb = q * 4;
      float wl0 = wlA[(kb + 0) * DD + j];
      float wl1 = wlA[(kb + 1) * DD + j];
      float wl2 = wlA[(kb + 2) * DD + j];
      float wl3 = wlA[(kb + 3) * DD + j];
      float wr0 = wrA[(kb + 0) * DD + j];
      float wr1 = wrA[(kb + 1) * DD + j];
      float wr2 = wrA[(kb + 2) * DD + j];
      float wr3 = wrA[(kb + 3) * DD + j];
      #pragma unroll
      for (int i = 0; i < 8; ++i) {
        float4 sv = *(const float4*)&sp[w][i][kb];   // broadcast (free)
        float4 pv = *(const float4*)&pp[w][i][kb];   // broadcast (free)
        float a = acc[i];
        a = fmaf(sv.x, wl0, a);
        a = fmaf(sv.y, wl1, a);
        a = fmaf(sv.z, wl2, a);
        a = fmaf(sv.w, wl3, a);
        a = fmaf(pv.x, wr0, a);
        a = fmaf(pv.y, wr1, a);
        a = fmaf(pv.z, wr2, a);
        a = fmaf(pv.w, wr3, a);
        acc[i] = a;
      }
    }

    // ---- per-node L2 normalize + relu + store ----
    #pragma unroll
    for (int i = 0; i < 8; ++i) {
      float a = acc[i];
      float ss = a * a;
      #pragma unroll
      for (int o2 = 32; o2 > 0; o2 >>= 1) ss += __shfl_xor(ss, o2, 64);
      float ov = a / fmaxf(sqrtf(ss), 1e-12f);
      if (relu) ov = fmaxf(ov, 0.0f);
      out[(size_t)(n0 + i) * DD + j] = ov;
    }
  }
}

// ---------------- fused post-MLP, 8 nodes/wave ----------------
__launch_bounds__(512, 4)
__global__ void post_kernel(const float* __restrict__ h,
                            const float* __restrict__ w1,
                            const float* __restrict__ b1,
                            const float* __restrict__ w2,
                            const float* __restrict__ b2,
                            float* __restrict__ out) {
  __shared__ float w1A[DD * DD] __attribute__((aligned(16)));  // [k][j]
  __shared__ float w2A[DD * DD] __attribute__((aligned(16)));
  __shared__ float hp[8][8][DD] __attribute__((aligned(16)));
  __shared__ float tp[8][8][DD] __attribute__((aligned(16)));
  int tid = threadIdx.x;
  int j = tid & 63;
  int w = tid >> 6;

  for (int i = tid; i < DD * DD; i += 512) {
    int jj = i >> 6, kk = i & 63;
    w1A[kk * DD + jj] = w1[i];
    w2A[kk * DD + jj] = w2[i];
  }
  float bb1 = b1[j];
  float bb2 = b2[j];
  __syncthreads();

  const int ngrp = (NOCT + 7) / 8;
  for (int grp = blockIdx.x; grp < ngrp; grp += gridDim.x) {
    int o = grp * 8 + w;
    if (o >= NOCT) continue;
    int n0 = o * 8;

    #pragma unroll
    for (int i = 0; i < 8; ++i) hp[w][i][j] = h[(size_t)(n0 + i) * DD + j];

    float acc[8];
    #pragma unroll
    for (int i = 0; i < 8; ++i) acc[i] = bb1;
    #pragma unroll
    for (int q = 0; q < 16; ++q) {
      int kb = q * 4;
      float w0 = w1A[(kb + 0) * DD + j];
      float wv1 = w1A[(kb + 1) * DD + j];
      float wv2 = w1A[(kb + 2) * DD + j];
      float wv3 = w1A[(kb + 3) * DD + j];
      #pragma unroll
      for (int i = 0; i < 8; ++i) {
        float4 hv = *(const float4*)&hp[w][i][kb];
        float a = acc[i];
        a = fmaf(hv.x, w0, a);
        a = fmaf(hv.y, wv1, a);
        a = fmaf(hv.z, wv2, a);
        a = fmaf(hv.w, wv3, a);
        acc[i] = a;
      }
    }
    #pragma unroll
    for (int i = 0; i < 8; ++i) tp[w][i][j] = acc[i];

    float acc2[8];
    #pragma unroll
    for (int i = 0; i < 8; ++i) acc2[i] = bb2;
    #pragma unroll
    for (int q = 0; q < 16; ++q) {
      int kb = q * 4;
      float w0 = w2A[(kb + 0) * DD + j];
      float wv1 = w2A[(kb + 1) * DD + j];
      float wv2 = w2A[(kb + 2) * DD + j];
      float wv3 = w2A[(kb + 3) * DD + j];
      #pragma unroll
      for (int i = 0; i < 8; ++i) {
        float4 tv = *(const float4*)&tp[w][i][kb];
        float a = acc2[i];
        a = fmaf(tv.x, w0, a);
        a = fmaf(tv.y, wv1, a);
        a = fmaf(tv.z, wv2, a);
        a = fmaf(tv.w, wv3, a);
        acc2[i] = a;
      }
    }
    #pragma unroll
    for (int i = 0; i < 8; ++i) out[(size_t)(n0 + i) * DD + j] = acc2[i];
  }
}

extern "C" void kernel_launch(void* const* d_in, const int* in_sizes, int n_in,
                              void* d_out, int out_size, void* d_ws, size_t ws_size,
                              hipStream_t stream) {
  const float* x   = (const float*)d_in[0];
  const int*   ei  = (const int*)d_in[1];
  const float* w1l = (const float*)d_in[2];
  const float* b1l = (const float*)d_in[3];
  const float* w1r = (const float*)d_in[4];
  const float* b1r = (const float*)d_in[5];
  const float* w2l = (const float*)d_in[6];
  const float* b2l = (const float*)d_in[7];
  const float* w2r = (const float*)d_in[8];
  const float* b2r = (const float*)d_in[9];
  const float* wp1 = (const float*)d_in[10];
  const float* bp1 = (const float*)d_in[11];
  const float* wp2 = (const float*)d_in[12];
  const float* bp2 = (const float*)d_in[13];
  float* out = (float*)d_out;

  const int* src = ei;
  const int* dst = ei + NE;

  // workspace (4B units): deg[102400] | cur[102400] | off[102400] | bsum[1024]
  //                      | adj[NE] | h[NN*DD]
  int* deg  = (int*)d_ws;
  int* cur  = deg + 102400;
  int* off  = cur + 102400;
  int* bsum = off + 102400;
  int* adj  = bsum + 1024;
  float* h  = (float*)(adj + NE);

  const int e4grid = (NE / 4 + 255) / 256;   // 1563

  // ---- build CSR once (reused by both layers) ----
  zero_kernel<<<512, 256, 0, stream>>>(deg, 204800);            // deg + cur
  hist_kernel<<<e4grid, 256, 0, stream>>>(dst, deg);
  scan1_kernel<<<NBLK, SCAN_BS, 0, stream>>>(deg, off, bsum);
  scan2_kernel<<<1, 512, 0, stream>>>(bsum);
  scan3_kernel<<<NBLK, SCAN_BS, 0, stream>>>(off, bsum);
  fill_kernel<<<e4grid, 256, 0, stream>>>(src, dst, off, cur, adj);

  // ---- layer 1: x -> h ----
  sage_kernel<<<512, 512, 0, stream>>>(x, off, deg, adj, w1l, b1l, w1r, b1r, h, 1);
  // ---- layer 2: h -> out ----
  sage_kernel<<<512, 512, 0, stream>>>(h, off, deg, adj, w2l, b2l, w2r, b2r, out, 1);
  // ---- post-MLP in-place on out ----
  post_kernel<<<512, 512, 0, stream>>>(out, wp1, bp1, wp2, bp2, out);
}

// Round 6
// 371.128 us; speedup vs baseline: 8.3912x; 1.1553x over previous
//
#include <hip/hip_runtime.h>

#define NN 100000
#define NE 1600000
#define DD 64
#define NOCT 12500                         // NN / 8 nodes-per-wave
#define SCAN_BS 256
#define NBLK ((NN + SCAN_BS - 1) / SCAN_BS)   // 391

// ---------------- zero ----------------
__global__ void zero_kernel(int* __restrict__ p, int n) {
  int i = blockIdx.x * blockDim.x + threadIdx.x;
  int stride = gridDim.x * blockDim.x;
  for (; i < n; i += stride) p[i] = 0;
}

// ---------------- degree histogram + rank record (int4 edges) ----------------
// rank[e] = arrival index of edge e within its dst bucket (from the same
// atomic that builds the histogram -> fill needs no atomics).
__global__ void hist_kernel(const int* __restrict__ dst, int* __restrict__ deg,
                            int* __restrict__ rank) {
  int e4 = blockIdx.x * 256 + threadIdx.x;
  if (e4 >= NE / 4) return;
  int4 d = reinterpret_cast<const int4*>(dst)[e4];
  int4 r;
  r.x = atomicAdd(&deg[d.x], 1);
  r.y = atomicAdd(&deg[d.y], 1);
  r.z = atomicAdd(&deg[d.z], 1);
  r.w = atomicAdd(&deg[d.w], 1);
  reinterpret_cast<int4*>(rank)[e4] = r;          // coalesced
}

// ---------------- scan stage 1 ----------------
__global__ void scan1_kernel(const int* __restrict__ deg, int* __restrict__ off,
                             int* __restrict__ bsum) {
  __shared__ int wsum[4];
  int i = blockIdx.x * SCAN_BS + threadIdx.x;
  int lane = threadIdx.x & 63, g = threadIdx.x >> 6;
  int v = (i < NN) ? deg[i] : 0;
  int incl = v;
  #pragma unroll
  for (int o = 1; o < 64; o <<= 1) {
    int t = __shfl_up(incl, o, 64);
    if (lane >= o) incl += t;
  }
  if (lane == 63) wsum[g] = incl;
  __syncthreads();
  int prefix = 0;
  for (int w = 0; w < g; ++w) prefix += wsum[w];
  if (i < NN) off[i] = prefix + incl - v;
  if (threadIdx.x == SCAN_BS - 1) bsum[blockIdx.x] = prefix + incl;
}

// ---------------- scan stage 2 ----------------
__global__ void scan2_kernel(int* __restrict__ bsum) {
  __shared__ int tmp[512];
  int i = threadIdx.x;
  int v = (i < NBLK) ? bsum[i] : 0;
  tmp[i] = v;
  __syncthreads();
  for (int o = 1; o < 512; o <<= 1) {
    int t = (i >= o) ? tmp[i - o] : 0;
    __syncthreads();
    tmp[i] += t;
    __syncthreads();
  }
  if (i < NBLK) bsum[i] = tmp[i] - v;
}

// ---------------- scan stage 3 ----------------
__global__ void scan3_kernel(int* __restrict__ off, const int* __restrict__ bsum) {
  int i = blockIdx.x * SCAN_BS + threadIdx.x;
  if (i < NN) off[i] += bsum[blockIdx.x];
}

// ---------------- CSR fill: NO atomics (uses precomputed rank) ----------------
__global__ void fill_kernel(const int* __restrict__ src, const int* __restrict__ dst,
                            const int* __restrict__ off, const int* __restrict__ rank,
                            int* __restrict__ adj) {
  int e4 = blockIdx.x * 256 + threadIdx.x;
  if (e4 >= NE / 4) return;
  int4 d = reinterpret_cast<const int4*>(dst)[e4];
  int4 s = reinterpret_cast<const int4*>(src)[e4];
  int4 r = reinterpret_cast<const int4*>(rank)[e4];
  adj[off[d.x] + r.x] = s.x;
  adj[off[d.y] + r.y] = s.y;
  adj[off[d.z] + r.z] = s.z;
  adj[off[d.w] + r.w] = s.w;
}

// ---------------- gather-mean: prop[n] = mean of x[neighbors] --------------
// No LDS, low VGPR -> full occupancy; 8 row-loads in flight per wave.
__launch_bounds__(256)
__global__ void gather_kernel(const float* __restrict__ x,
                              const int* __restrict__ off,
                              const int* __restrict__ deg,
                              const int* __restrict__ adj,
                              float* __restrict__ prop) {
  int wid = (blockIdx.x * 256 + threadIdx.x) >> 6;
  int nwaves = (gridDim.x * 256) >> 6;
  int j = threadIdx.x & 63;
  for (int n = wid; n < NN; n += nwaves) {
    int start = __builtin_amdgcn_readfirstlane(off[n]);
    int d     = __builtin_amdgcn_readfirstlane(deg[n]);
    float a0 = 0.f, a1 = 0.f, a2 = 0.f, a3 = 0.f;
    float a4 = 0.f, a5 = 0.f, a6 = 0.f, a7 = 0.f;
    int t = 0;
    for (; t + 8 <= d; t += 8) {
      int s0 = adj[start + t + 0];
      int s1 = adj[start + t + 1];
      int s2 = adj[start + t + 2];
      int s3 = adj[start + t + 3];
      int s4 = adj[start + t + 4];
      int s5 = adj[start + t + 5];
      int s6 = adj[start + t + 6];
      int s7 = adj[start + t + 7];
      a0 += x[(size_t)s0 * DD + j];
      a1 += x[(size_t)s1 * DD + j];
      a2 += x[(size_t)s2 * DD + j];
      a3 += x[(size_t)s3 * DD + j];
      a4 += x[(size_t)s4 * DD + j];
      a5 += x[(size_t)s5 * DD + j];
      a6 += x[(size_t)s6 * DD + j];
      a7 += x[(size_t)s7 * DD + j];
    }
    if (t < d) {                      // uniform masked tail (<=7 rows)
      int dm = d - 1;
      int u1 = (t + 1 < d) ? t + 1 : dm;
      int u2 = (t + 2 < d) ? t + 2 : dm;
      int u3 = (t + 3 < d) ? t + 3 : dm;
      int u4 = (t + 4 < d) ? t + 4 : dm;
      int u5 = (t + 5 < d) ? t + 5 : dm;
      int u6 = (t + 6 < d) ? t + 6 : dm;
      int s0 = adj[start + t];
      int s1 = adj[start + u1];
      int s2 = adj[start + u2];
      int s3 = adj[start + u3];
      int s4 = adj[start + u4];
      int s5 = adj[start + u5];
      int s6 = adj[start + u6];
      float v0 = x[(size_t)s0 * DD + j];
      float v1 = x[(size_t)s1 * DD + j];
      float v2 = x[(size_t)s2 * DD + j];
      float v3 = x[(size_t)s3 * DD + j];
      float v4 = x[(size_t)s4 * DD + j];
      float v5 = x[(size_t)s5 * DD + j];
      float v6 = x[(size_t)s6 * DD + j];
      a0 += v0;
      a1 += (t + 1 < d) ? v1 : 0.f;
      a2 += (t + 2 < d) ? v2 : 0.f;
      a3 += (t + 3 < d) ? v3 : 0.f;
      a4 += (t + 4 < d) ? v4 : 0.f;
      a5 += (t + 5 < d) ? v5 : 0.f;
      a6 += (t + 6 < d) ? v6 : 0.f;
    }
    float sum = ((a0 + a1) + (a2 + a3)) + ((a4 + a5) + (a6 + a7));
    float rc = 1.0f / fmaxf((float)d, 1.0f);
    prop[(size_t)n * DD + j] = sum * rc;
  }
}

// ---------------- dense SAGE GEMM: out = norm(x@wl.T + prop@wr.T + b), relu --
// 8 waves x 8 nodes; wave-local staging -> no in-loop syncs.
// Safe when out == xin (row-local: row staged before written).
__launch_bounds__(512, 4)
__global__ void sage_gemm_kernel(const float* __restrict__ xin,
                                 const float* __restrict__ prop,
                                 const float* __restrict__ wl,
                                 const float* __restrict__ bl,
                                 const float* __restrict__ wr,
                                 const float* __restrict__ br,
                                 float* __restrict__ out) {
  __shared__ float wlA[DD * DD] __attribute__((aligned(16)));  // [k][j]
  __shared__ float wrA[DD * DD] __attribute__((aligned(16)));  // [k][j]
  __shared__ float sp[8][8][DD] __attribute__((aligned(16)));
  __shared__ float pp[8][8][DD] __attribute__((aligned(16)));
  int tid = threadIdx.x;
  int j = tid & 63;
  int w = tid >> 6;

  for (int i = tid; i < DD * DD; i += 512) {
    int jj = i >> 6, kk = i & 63;
    wlA[kk * DD + jj] = wl[i];
    wrA[kk * DD + jj] = wr[i];
  }
  float bias = bl[j] + br[j];
  __syncthreads();

  const int ngrp = (NOCT + 7) / 8;   // 1563
  for (int grp = blockIdx.x; grp < ngrp; grp += gridDim.x) {
    int o = grp * 8 + w;
    if (o >= NOCT) continue;
    int n0 = o * 8;

    #pragma unroll
    for (int i = 0; i < 8; ++i) {
      sp[w][i][j] = xin[(size_t)(n0 + i) * DD + j];
      pp[w][i][j] = prop[(size_t)(n0 + i) * DD + j];
    }

    float acc[8];
    #pragma unroll
    for (int i = 0; i < 8; ++i) acc[i] = bias;

    #pragma unroll
    for (int q = 0; q < 16; ++q) {
      int kb = q * 4;
      float wl0 = wlA[(kb + 0) * DD + j];
      float wl1 = wlA[(kb + 1) * DD + j];
      float wl2 = wlA[(kb + 2) * DD + j];
      float wl3 = wlA[(kb + 3) * DD + j];
      float wr0 = wrA[(kb + 0) * DD + j];
      float wr1 = wrA[(kb + 1) * DD + j];
      float wr2 = wrA[(kb + 2) * DD + j];
      float wr3 = wrA[(kb + 3) * DD + j];
      #pragma unroll
      for (int i = 0; i < 8; ++i) {
        float4 sv = *(const float4*)&sp[w][i][kb];   // broadcast
        float4 pv = *(const float4*)&pp[w][i][kb];   // broadcast
        float a = acc[i];
        a = fmaf(sv.x, wl0, a);
        a = fmaf(sv.y, wl1, a);
        a = fmaf(sv.z, wl2, a);
        a = fmaf(sv.w, wl3, a);
        a = fmaf(pv.x, wr0, a);
        a = fmaf(pv.y, wr1, a);
        a = fmaf(pv.z, wr2, a);
        a = fmaf(pv.w, wr3, a);
        acc[i] = a;
      }
    }

    #pragma unroll
    for (int i = 0; i < 8; ++i) {
      float a = acc[i];
      float ss = a * a;
      #pragma unroll
      for (int o2 = 32; o2 > 0; o2 >>= 1) ss += __shfl_xor(ss, o2, 64);
      float ov = a / fmaxf(sqrtf(ss), 1e-12f);
      ov = fmaxf(ov, 0.0f);
      out[(size_t)(n0 + i) * DD + j] = ov;
    }
  }
}

// ---------------- combine post weights: wc = w2@w1, bc = w2@b1 + b2 ---------
__global__ void combine_kernel(const float* __restrict__ w1, const float* __restrict__ b1,
                               const float* __restrict__ w2, const float* __restrict__ b2,
                               float* __restrict__ wc, float* __restrict__ bc) {
  int t = threadIdx.x;
  for (int idx = t; idx < DD * DD; idx += 512) {
    int jp = idx >> 6, k = idx & 63;
    float s = 0.f;
    #pragma unroll
    for (int m = 0; m < DD; ++m) s = fmaf(w2[jp * DD + m], w1[m * DD + k], s);
    wc[idx] = s;
  }
  if (t < DD) {
    float s = b2[t];
    #pragma unroll
    for (int m = 0; m < DD; ++m) s = fmaf(w2[t * DD + m], b1[m], s);
    bc[t] = s;
  }
}

// ---------------- post-MLP as a single GEMM (in-place safe) ----------------
__launch_bounds__(512, 4)
__global__ void post_kernel(const float* __restrict__ h,
                            const float* __restrict__ wc,
                            const float* __restrict__ bc,
                            float* __restrict__ out) {
  __shared__ float wA[DD * DD] __attribute__((aligned(16)));   // [k][j]
  __shared__ float hp[8][8][DD] __attribute__((aligned(16)));
  int tid = threadIdx.x;
  int j = tid & 63;
  int w = tid >> 6;

  for (int i = tid; i < DD * DD; i += 512) {
    int jj = i >> 6, kk = i & 63;
    wA[kk * DD + jj] = wc[i];
  }
  float bb = bc[j];
  __syncthreads();

  const int ngrp = (NOCT + 7) / 8;
  for (int grp = blockIdx.x; grp < ngrp; grp += gridDim.x) {
    int o = grp * 8 + w;
    if (o >= NOCT) continue;
    int n0 = o * 8;
    #pragma unroll
    for (int i = 0; i < 8; ++i) hp[w][i][j] = h[(size_t)(n0 + i) * DD + j];

    float acc[8];
    #pragma unroll
    for (int i = 0; i < 8; ++i) acc[i] = bb;
    #pragma unroll
    for (int q = 0; q < 16; ++q) {
      int kb = q * 4;
      float w0 = wA[(kb + 0) * DD + j];
      float w1v = wA[(kb + 1) * DD + j];
      float w2v = wA[(kb + 2) * DD + j];
      float w3v = wA[(kb + 3) * DD + j];
      #pragma unroll
      for (int i = 0; i < 8; ++i) {
        float4 hv = *(const float4*)&hp[w][i][kb];
        float a = acc[i];
        a = fmaf(hv.x, w0, a);
        a = fmaf(hv.y, w1v, a);
        a = fmaf(hv.z, w2v, a);
        a = fmaf(hv.w, w3v, a);
        acc[i] = a;
      }
    }
    #pragma unroll
    for (int i = 0; i < 8; ++i) out[(size_t)(n0 + i) * DD + j] = acc[i];
  }
}

extern "C" void kernel_launch(void* const* d_in, const int* in_sizes, int n_in,
                              void* d_out, int out_size, void* d_ws, size_t ws_size,
                              hipStream_t stream) {
  const float* x   = (const float*)d_in[0];
  const int*   ei  = (const int*)d_in[1];
  const float* w1l = (const float*)d_in[2];
  const float* b1l = (const float*)d_in[3];
  const float* w1r = (const float*)d_in[4];
  const float* b1r = (const float*)d_in[5];
  const float* w2l = (const float*)d_in[6];
  const float* b2l = (const float*)d_in[7];
  const float* w2r = (const float*)d_in[8];
  const float* b2r = (const float*)d_in[9];
  const float* wp1 = (const float*)d_in[10];
  const float* bp1 = (const float*)d_in[11];
  const float* wp2 = (const float*)d_in[12];
  const float* bp2 = (const float*)d_in[13];
  float* out = (float*)d_out;

  const int* src = ei;
  const int* dst = ei + NE;

  // ws (4B units): deg[102400] | off[102400] | bsum[1024] | wc[4096] | bc[64+rest pad 1024]
  //               | adj[NE] | prop[NN*DD]  (rank aliases prop: dead before prop written)
  int* deg   = (int*)d_ws;
  int* off   = deg + 102400;
  int* bsum  = off + 102400;
  float* wc  = (float*)(bsum + 1024);
  float* bc  = wc + 4096;
  int* adj   = (int*)(bc + 1024);
  float* prop = (float*)(adj + NE);
  int* rank  = (int*)prop;                 // alias (used only before gather)

  const int e4grid = (NE / 4 + 255) / 256;   // 1563

  // ---- build CSR once ----
  zero_kernel<<<256, 256, 0, stream>>>(deg, 102400);
  hist_kernel<<<e4grid, 256, 0, stream>>>(dst, deg, rank);
  scan1_kernel<<<NBLK, SCAN_BS, 0, stream>>>(deg, off, bsum);
  scan2_kernel<<<1, 512, 0, stream>>>(bsum);
  scan3_kernel<<<NBLK, SCAN_BS, 0, stream>>>(off, bsum);
  fill_kernel<<<e4grid, 256, 0, stream>>>(src, dst, off, rank, adj);
  combine_kernel<<<1, 512, 0, stream>>>(wp1, bp1, wp2, bp2, wc, bc);

  // ---- layer 1: gather(x)->prop; gemm(x,prop)->out ----
  gather_kernel<<<2048, 256, 0, stream>>>(x, off, deg, adj, prop);
  sage_gemm_kernel<<<512, 512, 0, stream>>>(x, prop, w1l, b1l, w1r, b1r, out);

  // ---- layer 2: gather(out)->prop; gemm(out,prop)->out (in-place safe) ----
  gather_kernel<<<2048, 256, 0, stream>>>(out, off, deg, adj, prop);
  sage_gemm_kernel<<<512, 512, 0, stream>>>(out, prop, w2l, b2l, w2r, b2r, out);

  // ---- post-MLP (single combined GEMM, in-place) ----
  post_kernel<<<512, 512, 0, stream>>>(out, wc, bc, out);
}